// Round 1
// baseline (84.818 us; speedup 1.0000x reference)
//
#include <hip/hip_runtime.h>
#include <math.h>

// DTM layer: B=32, N=1024, D=2, M0=0.05, R=2
// out[b,n] = sqrt( (1/wb) * [ sum_{d2<t*} d2*w  +  t2*(wb - S_strict) ] )
// where t* = weighted quantile: inf{ t : sum_{d2<=t} w >= wb }, wb = 0.05*sum_b(w)

constexpr int N_GRID   = 1024;
constexpr int PER_LANE = 16;     // 1024 / 64
constexpr float M0_    = 0.05f;

__device__ __forceinline__ float wave_reduce_sum(float v) {
    #pragma unroll
    for (int off = 32; off > 0; off >>= 1)
        v += __shfl_xor(v, off, 64);
    return v;   // butterfly: all 64 lanes hold the total
}

__device__ __forceinline__ float wave_reduce_max(float v) {
    #pragma unroll
    for (int off = 32; off > 0; off >>= 1)
        v = fmaxf(v, __shfl_xor(v, off, 64));
    return v;
}

__global__ __launch_bounds__(256) void dtm_kernel(
    const float* __restrict__ input,   // [B, N, 2]
    const float* __restrict__ weight,  // [B, N]
    const float* __restrict__ grid,    // [N, 2]
    float* __restrict__ out)           // [B, N]
{
    const int wave = threadIdx.x >> 6;              // 0..3
    const int lane = threadIdx.x & 63;
    const int q    = (blockIdx.x << 2) + wave;      // query index in [0, B*N)
    const int b    = q >> 10;                       // q / 1024

    // query point (wave-uniform broadcast load)
    const float2 xq = reinterpret_cast<const float2*>(input)[q];

    // cache this lane's 16 grid points' d2 and weights in registers
    const float2* g2 = reinterpret_cast<const float2*>(grid);
    const float*  wrow = weight + b * N_GRID;

    float d2[PER_LANE], w[PER_LANE];
    float wsum = 0.f;
    #pragma unroll
    for (int k = 0; k < PER_LANE; ++k) {
        const int j = lane + (k << 6);              // coalesced: lane-contiguous
        const float2 g = g2[j];
        const float wj = wrow[j];
        const float dx = xq.x - g.x;
        const float dy = xq.y - g.y;
        d2[k] = dx * dx + dy * dy;
        w[k]  = wj;
        wsum += wj;
    }
    const float wb = M0_ * wave_reduce_sum(wsum);

    // hi = bits(max d2): valid upper bound with W(hi) = total >= wb
    float mx = d2[0];
    #pragma unroll
    for (int k = 1; k < PER_LANE; ++k) mx = fmaxf(mx, d2[k]);
    mx = wave_reduce_max(mx);

    // binary search on uint bit pattern of d2 (monotone for d2 >= 0):
    // find minimal u with  W(u) = sum_{bits(d2)<=u} w  >= wb.
    unsigned lo = 0u, hi = __float_as_uint(mx);
    while (lo < hi) {                               // wave-uniform loop
        const unsigned mid = (lo + hi) >> 1;
        const float t = __uint_as_float(mid);
        float s = 0.f;
        #pragma unroll
        for (int k = 0; k < PER_LANE; ++k)
            s += (d2[k] <= t) ? w[k] : 0.f;
        s = wave_reduce_sum(s);
        if (s >= wb) hi = mid;
        else         lo = mid + 1;
    }
    const float t2 = __uint_as_float(hi);           // an actual d2 value

    // final: A = sum_{d2 < t2} d2*w ; S = sum_{d2 < t2} w  (strict)
    float A = 0.f, S = 0.f;
    #pragma unroll
    for (int k = 0; k < PER_LANE; ++k) {
        const bool in = (d2[k] < t2);
        A += in ? d2[k] * w[k] : 0.f;
        S += in ? w[k] : 0.f;
    }
    A = wave_reduce_sum(A);
    S = wave_reduce_sum(S);

    const float val = (A + t2 * (wb - S)) / wb;
    if (lane == 0) out[q] = sqrtf(val);
}

extern "C" void kernel_launch(void* const* d_in, const int* in_sizes, int n_in,
                              void* d_out, int out_size, void* d_ws, size_t ws_size,
                              hipStream_t stream) {
    const float* input  = (const float*)d_in[0];   // [32,1024,2]
    const float* weight = (const float*)d_in[1];   // [32,1024]
    const float* grid   = (const float*)d_in[2];   // [1024,2]
    float* out = (float*)d_out;                    // [32,1024]

    const int total_q = 32 * 1024;                 // B*N
    dim3 blk(256);                                 // 4 waves/block, 1 query/wave
    dim3 grd(total_q / 4);                         // 8192 blocks
    hipLaunchKernelGGL(dtm_kernel, grd, blk, 0, stream,
                       input, weight, grid, out);
}